// Round 5
// baseline (698.232 us; speedup 1.0000x reference)
//
#include <hip/hip_runtime.h>
#include <stdint.h>

typedef unsigned short u16;

#define S_   7
#define B_   4096
#define D_   1024
#define E_   128
#define H_   512
#define V_   200
#define D0_  1152   // D+E
#define KX0  1664   // D0+H  (xcat width: [x | h0])
#define KX1  1024   // 2H    (x1cat width: [x1 | h1])
#define G4H  2048   // 4H

typedef __bf16 bf16x8 __attribute__((ext_vector_type(8)));
typedef float  f32x4  __attribute__((ext_vector_type(4)));
typedef u16    u16x8  __attribute__((ext_vector_type(8)));

__device__ __forceinline__ u16 f2bf(float f) {
  union { float f; uint32_t u; } v; v.f = f;
  uint32_t r = v.u + 0x7fffu + ((v.u >> 16) & 1u);   // RNE
  return (u16)(r >> 16);
}
__device__ __forceinline__ float bf2f(u16 b) {
  union { uint32_t u; float f; } v; v.u = ((uint32_t)b) << 16;
  return v.f;
}
__device__ __forceinline__ float sigmoidf_(float x) { return 1.0f / (1.0f + __expf(-x)); }
__device__ __forceinline__ float tanhf_(float x) {
  float t = __expf(-2.f * fabsf(x));
  return copysignf((1.f - t) / (1.f + t), x);
}

__device__ __forceinline__ void glds16(const u16* g, u16* l) {
  __builtin_amdgcn_global_load_lds(
      (const __attribute__((address_space(1))) uint32_t*)g,
      (__attribute__((address_space(3))) uint32_t*)l, 16, 0, 0);
}

__device__ __forceinline__ void cvt8(const float* src, u16x8* dst) {
  const float4* p = (const float4*)src;
  float4 x = p[0], y = p[1];
  u16x8 o;
  o[0]=f2bf(x.x); o[1]=f2bf(x.y); o[2]=f2bf(x.z); o[3]=f2bf(x.w);
  o[4]=f2bf(y.x); o[5]=f2bf(y.y); o[6]=f2bf(y.z); o[7]=f2bf(y.w);
  *dst = o;
}

// ---------- gates pack, 4-way ILP: [Wih|Whh] concat-K, gate-interleaved rows --
// chunk idx -> sr = idx/NG, kg = idx%NG.  src row sr = s*2048 + g*512 + j;
// dst row = s*2048 + (j>>4)*64 + g*16 + (j&15).
template<int KA, int KB, int KK>
__global__ void pack_gates4(const float* __restrict__ Wih, const float* __restrict__ Whh,
                            u16* __restrict__ dst) {
  const int NG = KK / 8;
  const int stride = gridDim.x * 256;
  int idx = blockIdx.x * 256 + threadIdx.x;
  long daddr[4]; const float* saddr[4];
  #pragma unroll
  for (int u = 0; u < 4; ++u) {
    int i = idx + u * stride;
    int sr = i / NG, kg = i - sr * NG;
    int k8 = kg * 8;
    long s = sr >> 11;
    int  r = sr & 2047;
    int  g = r >> 9, j = r & 511;
    long drow = (s << 11) + ((j >> 4) * 64 + g * 16 + (j & 15));
    daddr[u] = drow * KK + k8;
    saddr[u] = (k8 + 8 <= KA) ? (Wih + (long)sr * KA + k8)
                              : (Whh + (long)sr * KB + (k8 - KA));
  }
  float v[4][8];
  #pragma unroll
  for (int u = 0; u < 4; ++u) {
    const float4* p = (const float4*)saddr[u];
    float4 x = p[0], y = p[1];
    v[u][0]=x.x; v[u][1]=x.y; v[u][2]=x.z; v[u][3]=x.w;
    v[u][4]=y.x; v[u][5]=y.y; v[u][6]=y.z; v[u][7]=y.w;
  }
  #pragma unroll
  for (int u = 0; u < 4; ++u) {
    u16x8 o;
    #pragma unroll
    for (int q = 0; q < 8; ++q) o[q] = f2bf(v[u][q]);
    *(u16x8*)&dst[daddr[u]] = o;
  }
}

// ---------- highway/linear pack, 4-way ILP: [hw16|lin16] interleave ----------
template<int KS>
__global__ void pack_hl4(const float* __restrict__ src, u16* __restrict__ dst, int off16) {
  const int NG = KX0 / 8;   // 208
  const int stride = gridDim.x * 256;
  int idx = blockIdx.x * 256 + threadIdx.x;
  #pragma unroll
  for (int u = 0; u < 4; ++u) {
    int i = idx + u * stride;
    int sj = i / NG, kg = i - sj * NG;
    int k8 = kg * 8;
    long s = sj >> 9;
    int  j = sj & 511;
    long drow = (s << 10) + ((j >> 4) * 32 + off16 + (j & 15));
    u16x8 o;
    if (k8 + 8 <= KS) {
      cvt8(src + (long)sj * KS + k8, &o);
    } else {
      #pragma unroll
      for (int q = 0; q < 8; ++q) o[q] = 0;
    }
    *(u16x8*)&dst[drow * KX0 + k8] = o;
  }
}

// ---------- pred pack, 4-way ILP (identity rows, zero pad past D_) -----------
__global__ void pack_pred4(const float* __restrict__ pred, u16* __restrict__ dst) {
  const int NG = KX0 / 8;   // 208
  const int stride = gridDim.x * 256;
  int idx = blockIdx.x * 256 + threadIdx.x;
  #pragma unroll
  for (int u = 0; u < 4; ++u) {
    int i = idx + u * stride;
    int row = i / NG, kg = i - row * NG;
    int k8 = kg * 8;
    u16x8 o;
    if (k8 + 8 <= D_) {
      cvt8(pred + (long)row * D_ + k8, &o);
    } else {
      #pragma unroll
      for (int q = 0; q < 8; ++q) o[q] = 0;
    }
    *(u16x8*)&dst[(long)row * KX0 + k8] = o;
  }
}

__global__ void bias_sum(const float* __restrict__ a, const float* __restrict__ b,
                         float* __restrict__ o, int n) {
  int i = blockIdx.x * 256 + threadIdx.x;
  if (i < n) o[i] = a[i] + b[i];
}

__global__ void zero_f(float* __restrict__ p, int n) {
  for (int i = blockIdx.x * 256 + threadIdx.x; i < n; i += gridDim.x * 256) p[i] = 0.f;
}
__global__ void zero_u16k(u16* __restrict__ p, int n) {
  for (int i = blockIdx.x * 256 + threadIdx.x; i < n; i += gridDim.x * 256) p[i] = 0;
}

// ---------------- per-slot embedding gather into xcat[:,1024:1152] -----------
__global__ void gather_emb(const float* __restrict__ emb_s, const int* __restrict__ idx_s,
                           u16* __restrict__ xcat) {
  long b = blockIdx.x;
  int e = threadIdx.x;
  int ix = idx_s[b];
  xcat[b * KX0 + D_ + e] = f2bf(emb_s[(long)ix * E_ + e]);
}

// ---------------- fused bf16 MFMA GEMM + epilogue ----------------------------
// 128x128 tile, BK=64. 3-deep pipeline with COUNTED vmcnt (T4): A double-buffered
// (prefetch 1 ahead; A panel is L2-shared across col-blocks), W triple-buffered
// (prefetch 2 ahead; W streams from HBM). One raw "s_waitcnt vmcnt(N); s_barrier"
// per K-step -- in-flight prefetches survive the barrier. LDS = 80 KB -> exactly
// 2 blocks/CU. XOR-swizzled staging (linear gload_lds dest + pre-swizzled global
// source + swizzled ds_read). XCD-chunked blockIdx. 4 waves (2x2 of 64x64).
// MODE 0: LSTM cell epilogue (gate-interleaved weights; acc[m][0..3]=i,f,g,o).
// MODE 1: highway epilogue ([hw16|lin16] weights; reads h0 bf16 from xcat).
template<int MODE>
__global__ __launch_bounds__(256)
void gemm_fused(const u16* __restrict__ A, int lda,
                const u16* __restrict__ W, int ldw,
                int K, int ntn, int cpx,
                const float* __restrict__ bsum,   // MODE0: [2048]; MODE1: hwb [512]
                float* __restrict__ cbuf,         // MODE0 only
                u16* __restrict__ hdst, int hld, int hoff,
                float* __restrict__ hf32,         // MODE0 optional f32 h out (or null)
                const u16* __restrict__ xcat0) {  // MODE1: h0 bf16 source
  __shared__ __align__(16) u16 lds[(2 + 3) * 8192];   // A:2 bufs, W:3 bufs, 80 KiB
  u16* lA = lds;                 // + {0, 8192}
  u16* lW = lds + 2 * 8192;      // + {0, 8192, 16384}
  const int tid  = threadIdx.x;
  const int lane = tid & 63;
  const int wave = tid >> 6;
  const int p    = blockIdx.x;
  const int bid  = (p & 7) * cpx + (p >> 3);     // XCD-chunked remap (grid%8==0)
  const int tn = bid % ntn;
  const int tm = bid / ntn;
  const long row0 = (long)tm * 128;
  const long col0 = (long)tn * 128;
  const int wm = (wave >> 1) * 64;
  const int wn = (wave & 1) * 64;
  const int fr = lane & 15;
  const int fk = (lane >> 4) * 8;
  const int wr = wave * 32;

  // staging: wave covers rows [wr, wr+32), 4 issues of 8 rows; source col
  // pre-swizzled so linear LDS dest + XOR'd read return the right element.
  const int srow = wr + (lane >> 3);
  const int scol = ((lane & 7) ^ ((lane >> 3) & 7)) * 8;
  const u16* ga = A + (row0 + srow) * (long)lda + scol;
  const u16* gw = W + (col0 + srow) * (long)ldw + scol;
  const int dst0 = wr * 64 + lane * 8;

  // fragment read offsets (elements), XOR-swizzled within the 64-col row
  int aoff[4], woff[4];
  #pragma unroll
  for (int m = 0; m < 4; ++m) aoff[m] = (wm + m * 16 + fr) * 64;
  #pragma unroll
  for (int n = 0; n < 4; ++n) woff[n] = (wn + n * 16 + fr) * 64;
  const int swz = (fr & 7) << 3;
  const int kk0 = (0 + fk) ^ swz;
  const int kk1 = (32 + fk) ^ swz;

  f32x4 acc[4][4] = {};
  const int nt = K >> 6;

  auto stA = [&](int t, int b) {
    const u16* g = ga + ((long)t << 6);
    u16* d = lA + b * 8192 + dst0;
    #pragma unroll
    for (int i = 0; i < 4; ++i) glds16(g + (long)(i * 8) * lda, d + i * 512);
  };
  auto stW = [&](int t, int b) {
    const u16* g = gw + ((long)t << 6);
    u16* d = lW + b * 8192 + dst0;
    #pragma unroll
    for (int i = 0; i < 4; ++i) glds16(g + (long)(i * 8) * ldw, d + i * 512);
  };

  // prologue: A(0)->a0, W(0)->w0, W(1)->w1   (12 loads in flight)
  stA(0, 0);
  stW(0, 0);
  stW(1, 1);

  for (int t = 0; t < nt; ++t) {
    // wait tile t complete (A(t),W(t) are the oldest 8; allow W(t+1)'s 4 in flight),
    // then raw barrier -- prefetches survive.
    if (t + 1 < nt) asm volatile("s_waitcnt vmcnt(4)\n\ts_barrier" ::: "memory");
    else            asm volatile("s_waitcnt vmcnt(0)\n\ts_barrier" ::: "memory");
    // prefetch: A one ahead, W two ahead (issue after barrier: overwrite-safe)
    if (t + 1 < nt) stA(t + 1, (t + 1) & 1);
    if (t + 2 < nt) stW(t + 2, (t + 2) % 3);

    const u16* Ab = lA + (t & 1) * 8192;
    const u16* Wb = lW + (t % 3) * 8192;
    bf16x8 af0[4], wf0[4], af1[4], wf1[4];
    #pragma unroll
    for (int m = 0; m < 4; ++m) af0[m] = *(const bf16x8*)&Ab[aoff[m] + kk0];
    #pragma unroll
    for (int n = 0; n < 4; ++n) wf0[n] = *(const bf16x8*)&Wb[woff[n] + kk0];
    #pragma unroll
    for (int m = 0; m < 4; ++m) af1[m] = *(const bf16x8*)&Ab[aoff[m] + kk1];
    #pragma unroll
    for (int n = 0; n < 4; ++n) wf1[n] = *(const bf16x8*)&Wb[woff[n] + kk1];
    #pragma unroll
    for (int m = 0; m < 4; ++m)
      #pragma unroll
      for (int n = 0; n < 4; ++n)
        acc[m][n] = __builtin_amdgcn_mfma_f32_16x16x32_bf16(af0[m], wf0[n], acc[m][n], 0, 0, 0);
    #pragma unroll
    for (int m = 0; m < 4; ++m)
      #pragma unroll
      for (int n = 0; n < 4; ++n)
        acc[m][n] = __builtin_amdgcn_mfma_f32_16x16x32_bf16(af1[m], wf1[n], acc[m][n], 0, 0, 0);
  }

  const int cr = (lane >> 4) * 4;
  const int jg = wn >> 6;   // 0 or 1

  if (MODE == 0) {
    const int j = tn * 32 + jg * 16 + fr;
    const float bi = bsum[j], bf = bsum[512 + j], bg = bsum[1024 + j], bo = bsum[1536 + j];
    #pragma unroll
    for (int m = 0; m < 4; ++m) {
      const long rbase = row0 + wm + m * 16 + cr;
      #pragma unroll
      for (int r = 0; r < 4; ++r) {
        const long ri = rbase + r;
        float gi = acc[m][0][r] + bi;
        float gf = acc[m][1][r] + bf;
        float gg = acc[m][2][r] + bg;
        float go = acc[m][3][r] + bo;
        float cv = cbuf[ri * H_ + j];
        float cn = sigmoidf_(gf) * cv + sigmoidf_(gi) * tanhf_(gg);
        float hn = sigmoidf_(go) * tanhf_(cn);
        cbuf[ri * H_ + j] = cn;
        hdst[ri * hld + hoff + j] = f2bf(hn);
        if (hf32) hf32[ri * H_ + j] = hn;
      }
    }
  } else {
    #pragma unroll
    for (int pp = 0; pp < 2; ++pp) {
      const int j = tn * 64 + jg * 32 + pp * 16 + fr;
      const float bj = bsum[j];
      #pragma unroll
      for (int m = 0; m < 4; ++m) {
        const long rbase = row0 + wm + m * 16 + cr;
        #pragma unroll
        for (int r = 0; r < 4; ++r) {
          const long ri = rbase + r;
          float gv = sigmoidf_(acc[m][2 * pp][r] + bj);
          float h0 = bf2f(xcat0[ri * KX0 + D0_ + j]);
          float x1 = gv * h0 + (1.f - gv) * acc[m][2 * pp + 1][r];
          hdst[ri * hld + hoff + j] = f2bf(x1);
        }
      }
    }
  }
}

extern "C" void kernel_launch(void* const* d_in, const int* in_sizes, int n_in,
                              void* d_out, int out_size, void* d_ws, size_t ws_size,
                              hipStream_t stream) {
  const float* pred   = (const float*)d_in[0];
  const int*   labels = (const int*)d_in[1];
  const float* emb    = (const float*)d_in[2];
  const float* Wih0   = (const float*)d_in[3];
  const float* Whh0   = (const float*)d_in[4];
  const float* bih0   = (const float*)d_in[5];
  const float* bhh0   = (const float*)d_in[6];
  const float* hwW0   = (const float*)d_in[7];
  const float* hwb0   = (const float*)d_in[8];
  const float* linW0  = (const float*)d_in[9];
  const float* Wih1   = (const float*)d_in[10];
  const float* Whh1   = (const float*)d_in[11];
  const float* bih1   = (const float*)d_in[12];
  const float* bhh1   = (const float*)d_in[13];
  float* out = (float*)d_out;

  char* ws = (char*)d_ws;
  size_t off = 0;
  auto alloc = [&](size_t bytes) {
    char* p = ws + off;
    off = (off + bytes + 255) & ~(size_t)255;
    return p;
  };
  u16* WC0   = (u16*)alloc((size_t)S_ * G4H * KX0 * 2);   // gate-interleaved [Wih0|Whh0]
  u16* WHL   = (u16*)alloc((size_t)S_ * 1024 * KX0 * 2);  // [hw16|lin16] interleave
  u16* WC1   = (u16*)alloc((size_t)S_ * G4H * KX1 * 2);   // gate-interleaved [Wih1|Whh1]
  u16* xcat  = (u16*)alloc((size_t)B_ * KX0 * 2);         // [pred|emb|h0] bf16
  u16* x1cat = (u16*)alloc((size_t)B_ * KX1 * 2);         // [x1|h1] bf16
  float* c0   = (float*)alloc((size_t)B_ * H_ * 4);
  float* c1   = (float*)alloc((size_t)B_ * H_ * 4);
  float* bs0  = (float*)alloc((size_t)S_ * G4H * 4);      // bih0+bhh0
  float* bs1  = (float*)alloc((size_t)S_ * G4H * 4);      // bih1+bhh1

  // -------- phase A: weight conversion + state init ---------------------------
  // exact grids: total_chunks / (256 threads * 4 ILP)
  pack_gates4<D0_, H_, KX0><<<2912, 256, 0, stream>>>(Wih0, Whh0, WC0);  // 7*2048*208/1024
  pack_gates4<H_,  H_, KX1><<<1792, 256, 0, stream>>>(Wih1, Whh1, WC1);  // 7*2048*128/1024
  pack_hl4<KX0><<<728, 256, 0, stream>>>(hwW0,  WHL, 0);                 // 7*512*208/1024
  pack_hl4<D0_><<<728, 256, 0, stream>>>(linW0, WHL, 16);
  pack_pred4<<<832, 256, 0, stream>>>(pred, xcat);                       // 4096*208/1024
  bias_sum<<<(S_ * G4H + 255) / 256, 256, 0, stream>>>(bih0, bhh0, bs0, S_ * G4H);
  bias_sum<<<(S_ * G4H + 255) / 256, 256, 0, stream>>>(bih1, bhh1, bs1, S_ * G4H);
  zero_f<<<256, 256, 0, stream>>>(c0, B_ * H_);
  zero_f<<<256, 256, 0, stream>>>(c1, B_ * H_);
  zero_u16k<<<256, 256, 0, stream>>>(x1cat, B_ * KX1);

  const int g0 = (B_ / 128) * (G4H / 128);    // 512 blocks (= 2/CU, all resident)
  const int g1 = (B_ / 128) * (1024 / 128);   // 256 blocks

  // -------- sequential slot loop ----------------------------------------------
  for (int s = 0; s < S_; ++s) {
    gather_emb<<<B_, E_, 0, stream>>>(emb + (size_t)s * V_ * E_, labels + (size_t)s * B_, xcat);

    // layer-0 gates + cell (fused): [x|h0] @ WC0^T, M=4096,N=2048,K=1664
    gemm_fused<0><<<g0, 256, 0, stream>>>(
        xcat, KX0, WC0 + (size_t)s * G4H * KX0, KX0, KX0, G4H / 128, g0 / 8,
        bs0 + (size_t)s * G4H, c0, xcat, KX0, D0_, nullptr, nullptr);

    // merged highway+linear + combine (fused): N=1024,K=1664
    gemm_fused<1><<<g1, 256, 0, stream>>>(
        xcat, KX0, WHL + (size_t)s * 1024 * KX0, KX0, KX0, 1024 / 128, g1 / 8,
        hwb0 + (size_t)s * H_, nullptr, x1cat, KX1, 0, nullptr, xcat);

    // layer-1 gates + cell (fused): [x1|h1] @ WC1^T, N=2048,K=1024
    gemm_fused<0><<<g0, 256, 0, stream>>>(
        x1cat, KX1, WC1 + (size_t)s * G4H * KX1, KX1, KX1, G4H / 128, g0 / 8,
        bs1 + (size_t)s * G4H, c1, x1cat, KX1, H_, out, nullptr);
  }
}